// Round 6
// baseline (149.357 us; speedup 1.0000x reference)
//
#include <hip/hip_runtime.h>
#include <hip/hip_bf16.h>

// N=8192 nodes, T=6 snapshots, chains = T-2 = 4, 3 steps per chain.
// Step: rv_new[i] = 1 - prod_j (1 - W[j][i]*rv[j]).  W ~0.2% dense.
// Pass 1 (HBM-bound): stream W once, build column-major packed edge list
//   (CAP slots/col, 8B {w,j}).  Nonzeros go through a per-block LDS queue
//   so the VMEM stream stays loads-only (vmcnt is issue-ordered; a global
//   atomic mid-stream would block retirement of all later loads).
// Pass 2: ALL 3 steps for all 4 chains in ONE dispatch: 1 block per chain,
//   rv ping-ponged in LDS, __syncthreads between steps.
// Floor = reading W once: 268 MB ~= 40 us.

#define CAP  64   // slots/column; Poisson(16.4): P(>=64) ~ e^-39
#define QMAX 256  // LDS queue entries/block; lambda ~66/block at 32 f4/thread

typedef float floatx4 __attribute__((ext_vector_type(4)));

template <bool POW2>
__global__ __launch_bounds__(256) void build_edges_kernel(
    const floatx4* __restrict__ W4, unsigned total4, unsigned log2N, unsigned maskN,
    int* __restrict__ cnt, uint2* __restrict__ epk, unsigned N) {
    __shared__ unsigned qcount;
    __shared__ unsigned qw[QMAX];
    __shared__ unsigned qji[QMAX];
    if (threadIdx.x == 0) qcount = 0u;
    __syncthreads();

    const unsigned gsize = gridDim.x * blockDim.x;
    unsigned e4 = blockIdx.x * blockDim.x + threadIdx.x;

    auto emit = [&](float w, unsigned j, unsigned i) {
        unsigned k = atomicAdd(&qcount, 1u);          // LDS atomic: lgkmcnt only
        if (k < QMAX) {
            qw[k]  = __float_as_uint(w);
            qji[k] = (j << 16) | i;                   // N <= 65536
        } else {                                      // ~never: direct fallback
            int s = atomicAdd(&cnt[i], 1);
            if (s < CAP) { uint2 p; p.x = __float_as_uint(w); p.y = j;
                           epk[(unsigned)s * N + i] = p; }
        }
    };
    auto process = [&](floatx4 v, unsigned e) {
        unsigned ored = __float_as_uint(v.x) | __float_as_uint(v.y) |
                        __float_as_uint(v.z) | __float_as_uint(v.w);
        if (ored == 0u) return;                       // weights >= 0
        unsigned j, i0;
        if (POW2) { j = e >> log2N; i0 = e & maskN; }
        else      { j = e / N;      i0 = e - j * N; }
#pragma unroll
        for (int t = 0; t < 4; ++t)
            if (v[t] != 0.0f) emit(v[t], j, i0 + t);
    };

    // 8 independent 16B loads in flight; no VMEM stores/atomics in stream.
    // (R4's regression was its serial collect-register chain, not the depth;
    //  the LDS queue has no cross-element register dependence.)
    for (; e4 + 7u * gsize < total4; e4 += 8u * gsize) {
        floatx4 v0 = W4[e4];
        floatx4 v1 = W4[e4 + gsize];
        floatx4 v2 = W4[e4 + 2u * gsize];
        floatx4 v3 = W4[e4 + 3u * gsize];
        floatx4 v4 = W4[e4 + 4u * gsize];
        floatx4 v5 = W4[e4 + 5u * gsize];
        floatx4 v6 = W4[e4 + 6u * gsize];
        floatx4 v7 = W4[e4 + 7u * gsize];
        process(v0, (e4) << 2);
        process(v1, (e4 + gsize) << 2);
        process(v2, (e4 + 2u * gsize) << 2);
        process(v3, (e4 + 3u * gsize) << 2);
        process(v4, (e4 + 4u * gsize) << 2);
        process(v5, (e4 + 5u * gsize) << 2);
        process(v6, (e4 + 6u * gsize) << 2);
        process(v7, (e4 + 7u * gsize) << 2);
    }
    for (; e4 < total4; e4 += gsize) process(W4[e4], e4 << 2);

    // flush queue (loads all retired; atomics can't stall them now)
    __syncthreads();
    unsigned qn = qcount < (unsigned)QMAX ? qcount : (unsigned)QMAX;
    for (unsigned t = threadIdx.x; t < qn; t += blockDim.x) {
        unsigned wbits = qw[t], ji = qji[t];
        unsigned i = ji & 0xffffu, j = ji >> 16;
        int s = atomicAdd(&cnt[i], 1);
        if (s < CAP) { uint2 p; p.x = wbits; p.y = j;
                       epk[(unsigned)s * N + i] = p; }
    }
}

// All propagation steps in one dispatch. One block per chain; rv ping-pongs
// in LDS; __syncthreads between steps (cheap vs kernel launch). CPT = columns
// per thread (compile-time so nn[] stays in registers, rule #20).
// Per-column product split into even/odd chains for ILP.
#define NMAX 8192
template <int CPT>
__global__ __launch_bounds__(1024) void steps_fused_kernel(
    const float* __restrict__ snaps,    // [T, N]
    float* __restrict__ out,            // [chains, N]
    const int* __restrict__ cnt,
    const uint2* __restrict__ epk,
    int N, int nsteps) {
    __shared__ float rvbuf[2][NMAX];
    const int c = blockIdx.x;
    const int tid = threadIdx.x;
    const int nthr = blockDim.x;

    // rv0 = snaps[c+1] - snaps[c]
    const floatx4* sa4 = (const floatx4*)(snaps + (size_t)(c + 1) * N);
    const floatx4* sb4 = (const floatx4*)(snaps + (size_t)c * N);
    floatx4* r04 = (floatx4*)rvbuf[0];
    for (int t = tid; t < N / 4; t += nthr) r04[t] = sa4[t] - sb4[t];

    int nn[CPT];
#pragma unroll
    for (int u = 0; u < CPT; ++u) {
        int i = tid + u * nthr;
        int n = cnt[i];
        nn[u] = n > CAP ? CAP : n;
    }
    __syncthreads();

    int cur = 0;
    for (int s = 0; s < nsteps; ++s) {
        const float* rv = rvbuf[cur];
        float* rn = rvbuf[cur ^ 1];
#pragma unroll
        for (int u = 0; u < CPT; ++u) {
            int i = tid + u * nthr;
            int n = nn[u];
            float pa = 1.0f, pb = 1.0f;
            int k = 0;
            for (; k + 1 < n; k += 2) {
                uint2 p0 = epk[(size_t)k * N + i];
                uint2 p1 = epk[(size_t)(k + 1) * N + i];
                pa *= 1.0f - __uint_as_float(p0.x) * rv[(int)p0.y];
                pb *= 1.0f - __uint_as_float(p1.x) * rv[(int)p1.y];
            }
            if (k < n) {
                uint2 p0 = epk[(size_t)k * N + i];
                pa *= 1.0f - __uint_as_float(p0.x) * rv[(int)p0.y];
            }
            rn[i] = 1.0f - pa * pb;
        }
        __syncthreads();
        cur ^= 1;
    }

    const floatx4* rc4 = (const floatx4*)rvbuf[cur];
    floatx4* o4 = (floatx4*)(out + (size_t)c * N);
    for (int t = tid; t < N / 4; t += nthr) o4[t] = rc4[t];
}

// Fallback per-step kernel (non-8192 N): lane-parallel, 32 lanes/column.
template <bool FIRST>
__global__ __launch_bounds__(256) void step_lp_kernel(
    const float* __restrict__ rv_in, const float* __restrict__ snaps,
    float* __restrict__ rv_out, const int* __restrict__ cnt,
    const uint2* __restrict__ epk, int N) {
    const int c    = blockIdx.y;
    const int lane = threadIdx.x & 31;
    const int grp  = threadIdx.x >> 5;
    const int i    = blockIdx.x * 8 + grp;
    if (i >= N) return;
    const float* rv = rv_in + (size_t)c * N;
    const float* sa = snaps + (size_t)(c + 1) * N;
    const float* sb = snaps + (size_t)c * N;
    int n = cnt[i];
    if (n > CAP) n = CAP;
    float prod = 1.0f;
    for (int k = lane; k < n; k += 32) {
        uint2 p = epk[(size_t)k * N + i];
        float r = FIRST ? (sa[(int)p.y] - sb[(int)p.y]) : rv[(int)p.y];
        prod *= 1.0f - __uint_as_float(p.x) * r;
    }
    for (int off = 16; off; off >>= 1) prod *= __shfl_xor(prod, off, 32);
    if (lane == 0) rv_out[(size_t)c * N + i] = 1.0f - prod;
}

extern "C" void kernel_launch(void* const* d_in, const int* in_sizes, int n_in,
                              void* d_out, int out_size, void* d_ws, size_t ws_size,
                              hipStream_t stream) {
    const float* snaps = (const float*)d_in[0];   // [T, N]
    const float* W     = (const float*)d_in[1];   // [N, N]
    // d_in[2] = time_pick (int64); step counts are static (=3)

    const int T = in_sizes[2];          // 6
    const int N = in_sizes[0] / T;      // 8192
    const int chains = T - 2;           // 4
    const int NSTEPS = 3;

    // workspace layout
    char* ws = (char*)d_ws;
    int*   cnt = (int*)ws;                                   // N ints
    size_t off = ((size_t)N * 4 + 255) & ~(size_t)255;
    float* rvA = (float*)(ws + off);                         // chains*N
    off += ((size_t)chains * N * 4 + 255) & ~(size_t)255;
    float* rvB = (float*)(ws + off);                         // chains*N
    off += ((size_t)chains * N * 4 + 255) & ~(size_t)255;
    uint2* epk = (uint2*)(ws + off);                         // CAP*N uint2 (4 MB)

    hipMemsetAsync(cnt, 0, (size_t)N * sizeof(int), stream);

    // build sparse structure: one streaming pass over W (32 f4/thread)
    const unsigned total4 = (unsigned)((size_t)N * N / 4);
    const bool pow2 = (N & (N - 1)) == 0;
    unsigned log2N = 0;
    while ((1u << log2N) < (unsigned)N) ++log2N;
    const int bblk = 256;
    int bgrd = (int)((total4 + (unsigned)bblk * 32 - 1) / ((unsigned)bblk * 32));
    if (bgrd < 1) bgrd = 1;
    if (pow2)
        build_edges_kernel<true><<<bgrd, bblk, 0, stream>>>(
            (const floatx4*)W, total4, log2N, (unsigned)N - 1, cnt, epk, (unsigned)N);
    else
        build_edges_kernel<false><<<bgrd, bblk, 0, stream>>>(
            (const floatx4*)W, total4, log2N, (unsigned)N - 1, cnt, epk, (unsigned)N);

    float* outp = (float*)d_out;
    if (N == 8192) {
        // all steps, all chains, one dispatch (CPT = 8192/1024 = 8)
        steps_fused_kernel<8><<<chains, 1024, 0, stream>>>(
            snaps, outp, cnt, epk, N, NSTEPS);
    } else {
        dim3 sgrd((N + 7) / 8, chains);
        float* out0 = (NSTEPS == 1) ? outp : rvA;
        step_lp_kernel<true><<<sgrd, 256, 0, stream>>>(nullptr, snaps, out0, cnt, epk, N);
        float* bufs[2] = {rvA, rvB};
        for (int s = 1; s < NSTEPS; ++s) {
            const float* in = bufs[(s - 1) & 1];
            float* out = (s == NSTEPS - 1) ? outp : bufs[s & 1];
            step_lp_kernel<false><<<sgrd, 256, 0, stream>>>(in, nullptr, out, cnt, epk, N);
        }
    }
}

// Round 7
// 76.289 us; speedup vs baseline: 1.9578x; 1.9578x over previous
//
#include <hip/hip_runtime.h>
#include <hip/hip_bf16.h>

// N=8192 nodes, T=6 snapshots, chains = T-2 = 4, 3 steps per chain.
// Step: rv_new[i] = 1 - prod_j (1 - W[j][i]*rv[j]).  W ~0.2% dense.
// Pass 1 (HBM-bound): stream W once, build column-major packed edge list
//   (CAP slots/col, 8B {w,j}).  Nonzeros go through a per-block LDS queue
//   so the VMEM stream stays loads-only (vmcnt is issue-ordered; a global
//   atomic mid-stream would block retirement of all later loads).
//   8 independent loads in flight/lane; 2048 blocks = 8/CU exactly.
// Pass 2: 3 lane-parallel step dispatches (4096 blocks each) — R6's
//   single-dispatch fusion at 4 blocks was a 90us disaster (4 CUs busy).
// Floor = reading W once: 268 MB ~= 40 us at ~6.8 TB/s.

#define CAP  64   // slots/column; Poisson(16.4): P(>=64) ~ e^-39
#define QMAX 256  // LDS queue entries/block; lambda ~66/block at 32 f4/thread

typedef float floatx4 __attribute__((ext_vector_type(4)));

template <bool POW2>
__global__ __launch_bounds__(256) void build_edges_kernel(
    const floatx4* __restrict__ W4, unsigned total4, unsigned log2N, unsigned maskN,
    int* __restrict__ cnt, uint2* __restrict__ epk, unsigned N) {
    __shared__ unsigned qcount;
    __shared__ unsigned qw[QMAX];
    __shared__ unsigned qji[QMAX];
    if (threadIdx.x == 0) qcount = 0u;
    __syncthreads();

    const unsigned gsize = gridDim.x * blockDim.x;
    unsigned e4 = blockIdx.x * blockDim.x + threadIdx.x;

    auto emit = [&](float w, unsigned j, unsigned i) {
        unsigned k = atomicAdd(&qcount, 1u);          // LDS atomic: lgkmcnt only
        if (k < QMAX) {
            qw[k]  = __float_as_uint(w);
            qji[k] = (j << 16) | i;                   // N <= 65536
        } else {                                      // ~never: direct fallback
            int s = atomicAdd(&cnt[i], 1);
            if (s < CAP) { uint2 p; p.x = __float_as_uint(w); p.y = j;
                           epk[(unsigned)s * N + i] = p; }
        }
    };
    auto process = [&](floatx4 v, unsigned e) {
        unsigned ored = __float_as_uint(v.x) | __float_as_uint(v.y) |
                        __float_as_uint(v.z) | __float_as_uint(v.w);
        if (ored == 0u) return;                       // weights >= 0
        unsigned j, i0;
        if (POW2) { j = e >> log2N; i0 = e & maskN; }
        else      { j = e / N;      i0 = e - j * N; }
#pragma unroll
        for (int t = 0; t < 4; ++t)
            if (v[t] != 0.0f) emit(v[t], j, i0 + t);
    };

    // 8 independent 16B loads in flight; no VMEM stores/atomics in stream.
    for (; e4 + 7u * gsize < total4; e4 += 8u * gsize) {
        floatx4 v0 = W4[e4];
        floatx4 v1 = W4[e4 + gsize];
        floatx4 v2 = W4[e4 + 2u * gsize];
        floatx4 v3 = W4[e4 + 3u * gsize];
        floatx4 v4 = W4[e4 + 4u * gsize];
        floatx4 v5 = W4[e4 + 5u * gsize];
        floatx4 v6 = W4[e4 + 6u * gsize];
        floatx4 v7 = W4[e4 + 7u * gsize];
        process(v0, (e4) << 2);
        process(v1, (e4 + gsize) << 2);
        process(v2, (e4 + 2u * gsize) << 2);
        process(v3, (e4 + 3u * gsize) << 2);
        process(v4, (e4 + 4u * gsize) << 2);
        process(v5, (e4 + 5u * gsize) << 2);
        process(v6, (e4 + 6u * gsize) << 2);
        process(v7, (e4 + 7u * gsize) << 2);
    }
    for (; e4 < total4; e4 += gsize) process(W4[e4], e4 << 2);

    // flush queue (loads all retired; atomics can't stall them now)
    __syncthreads();
    unsigned qn = qcount < (unsigned)QMAX ? qcount : (unsigned)QMAX;
    for (unsigned t = threadIdx.x; t < qn; t += blockDim.x) {
        unsigned wbits = qw[t], ji = qji[t];
        unsigned i = ji & 0xffffu, j = ji >> 16;
        int s = atomicAdd(&cnt[i], 1);
        if (s < CAP) { uint2 p; p.x = wbits; p.y = j;
                       epk[(unsigned)s * N + i] = p; }
    }
}

// Lane-parallel step: 32 lanes per column, 8 columns per 256-thread block
// -> 1024 x chains blocks, full machine. FIRST: rv = snaps[c+1]-snaps[c].
template <bool FIRST>
__global__ __launch_bounds__(256) void step_lp_kernel(
    const float* __restrict__ rv_in,    // [chains, N] (unused if FIRST)
    const float* __restrict__ snaps,    // [T, N]      (used if FIRST)
    float* __restrict__ rv_out,         // [chains, N]
    const int* __restrict__ cnt,
    const uint2* __restrict__ epk,
    int N) {
    const int c    = blockIdx.y;
    const int lane = threadIdx.x & 31;
    const int grp  = threadIdx.x >> 5;            // 0..7
    const int i    = blockIdx.x * 8 + grp;        // column
    if (i >= N) return;
    const float* rv = rv_in + (size_t)c * N;
    const float* sa = snaps + (size_t)(c + 1) * N;
    const float* sb = snaps + (size_t)c * N;
    int n = cnt[i];
    if (n > CAP) n = CAP;
    float prod = 1.0f;
    for (int k = lane; k < n; k += 32) {
        uint2 p = epk[(size_t)k * N + i];
        float w = __uint_as_float(p.x);
        int j = (int)p.y;
        float r = FIRST ? (sa[j] - sb[j]) : rv[j];
        prod *= 1.0f - w * r;
    }
    for (int off = 16; off; off >>= 1) prod *= __shfl_xor(prod, off, 32);
    if (lane == 0) rv_out[(size_t)c * N + i] = 1.0f - prod;
}

extern "C" void kernel_launch(void* const* d_in, const int* in_sizes, int n_in,
                              void* d_out, int out_size, void* d_ws, size_t ws_size,
                              hipStream_t stream) {
    const float* snaps = (const float*)d_in[0];   // [T, N]
    const float* W     = (const float*)d_in[1];   // [N, N]
    // d_in[2] = time_pick (int64); step counts are static (=3)

    const int T = in_sizes[2];          // 6
    const int N = in_sizes[0] / T;      // 8192
    const int chains = T - 2;           // 4
    const int NSTEPS = 3;

    // workspace layout
    char* ws = (char*)d_ws;
    int*   cnt = (int*)ws;                                   // N ints
    size_t off = ((size_t)N * 4 + 255) & ~(size_t)255;
    float* rvA = (float*)(ws + off);                         // chains*N
    off += ((size_t)chains * N * 4 + 255) & ~(size_t)255;
    float* rvB = (float*)(ws + off);                         // chains*N
    off += ((size_t)chains * N * 4 + 255) & ~(size_t)255;
    uint2* epk = (uint2*)(ws + off);                         // CAP*N uint2 (4 MB)

    hipMemsetAsync(cnt, 0, (size_t)N * sizeof(int), stream);

    // build sparse structure: one streaming pass over W (32 f4/thread,
    // 2048 blocks = exactly 8 resident blocks/CU across 256 CUs)
    const unsigned total4 = (unsigned)((size_t)N * N / 4);
    const bool pow2 = (N & (N - 1)) == 0;
    unsigned log2N = 0;
    while ((1u << log2N) < (unsigned)N) ++log2N;
    const int bblk = 256;
    int bgrd = (int)((total4 + (unsigned)bblk * 32 - 1) / ((unsigned)bblk * 32));
    if (bgrd < 1) bgrd = 1;
    if (pow2)
        build_edges_kernel<true><<<bgrd, bblk, 0, stream>>>(
            (const floatx4*)W, total4, log2N, (unsigned)N - 1, cnt, epk, (unsigned)N);
    else
        build_edges_kernel<false><<<bgrd, bblk, 0, stream>>>(
            (const floatx4*)W, total4, log2N, (unsigned)N - 1, cnt, epk, (unsigned)N);

    // propagation: lane-parallel steps; step 1 fuses the snapshot diff
    dim3 sgrd((N + 7) / 8, chains);
    float* outp = (float*)d_out;

    float* out0 = (NSTEPS == 1) ? outp : rvA;
    step_lp_kernel<true><<<sgrd, 256, 0, stream>>>(nullptr, snaps, out0, cnt, epk, N);
    float* bufs[2] = {rvA, rvB};
    for (int s = 1; s < NSTEPS; ++s) {
        const float* in = bufs[(s - 1) & 1];
        float* out = (s == NSTEPS - 1) ? outp : bufs[s & 1];
        step_lp_kernel<false><<<sgrd, 256, 0, stream>>>(in, nullptr, out, cnt, epk, N);
    }
}

// Round 8
// 70.285 us; speedup vs baseline: 2.1250x; 1.0854x over previous
//
#include <hip/hip_runtime.h>
#include <hip/hip_bf16.h>

// N=8192 nodes, T=6 snapshots, chains = T-2 = 4, 3 steps per chain.
// Step: rv_new[i] = 1 - prod_j (1 - W[j][i]*rv[j]).  W ~0.2% dense.
// Pass 1 (HBM-bound): stream W once, build a CSR-style packed edge list
//   (CAP slots/col, 8B {w,j}, epk[i*CAP+k]).  Nonzeros go through a
//   per-block LDS queue so the VMEM stream stays loads-only (vmcnt is
//   issue-ordered; a global atomic mid-stream blocks later loads).
//   Build config pinned to R5's measured-best: 4-deep, 16 f4/thread,
//   4096 blocks (R7 showed 8-deep/2048 regresses).
// Pass 2: 3 step dispatches; 16-lane group per (chain, column); CSR layout
//   makes each group's edge reads 128B-contiguous (R5-R7 layout epk[k*N+i]
//   cost one 64B line per 8B edge).
// Floor = reading W once: 268 MB ~= 42 us.

#define CAP  64   // slots/column; Poisson(16.4): P(>=64) ~ e^-39
#define QMAX 256  // LDS queue entries/block; lambda ~33/block at 16 f4/thread

typedef float floatx4 __attribute__((ext_vector_type(4)));

template <bool POW2>
__global__ __launch_bounds__(256) void build_edges_kernel(
    const floatx4* __restrict__ W4, unsigned total4, unsigned log2N, unsigned maskN,
    int* __restrict__ cnt, uint2* __restrict__ epk, unsigned N) {
    __shared__ unsigned qcount;
    __shared__ unsigned qw[QMAX];
    __shared__ unsigned qji[QMAX];
    if (threadIdx.x == 0) qcount = 0u;
    __syncthreads();

    const unsigned gsize = gridDim.x * blockDim.x;
    unsigned e4 = blockIdx.x * blockDim.x + threadIdx.x;

    auto emit = [&](float w, unsigned j, unsigned i) {
        unsigned k = atomicAdd(&qcount, 1u);          // LDS atomic: lgkmcnt only
        if (k < QMAX) {
            qw[k]  = __float_as_uint(w);
            qji[k] = (j << 16) | i;                   // N <= 65536
        } else {                                      // ~never: direct fallback
            int s = atomicAdd(&cnt[i], 1);
            if (s < CAP) { uint2 p; p.x = __float_as_uint(w); p.y = j;
                           epk[(size_t)i * CAP + s] = p; }
        }
    };
    auto process = [&](floatx4 v, unsigned e) {
        unsigned ored = __float_as_uint(v.x) | __float_as_uint(v.y) |
                        __float_as_uint(v.z) | __float_as_uint(v.w);
        if (ored == 0u) return;                       // weights >= 0
        unsigned j, i0;
        if (POW2) { j = e >> log2N; i0 = e & maskN; }
        else      { j = e / N;      i0 = e - j * N; }
#pragma unroll
        for (int t = 0; t < 4; ++t)
            if (v[t] != 0.0f) emit(v[t], j, i0 + t);
    };

    // 4 independent 16B loads in flight; no VMEM stores/atomics in stream
    for (; e4 + 3u * gsize < total4; e4 += 4u * gsize) {
        floatx4 v0 = W4[e4];
        floatx4 v1 = W4[e4 + gsize];
        floatx4 v2 = W4[e4 + 2u * gsize];
        floatx4 v3 = W4[e4 + 3u * gsize];
        process(v0, (e4) << 2);
        process(v1, (e4 + gsize) << 2);
        process(v2, (e4 + 2u * gsize) << 2);
        process(v3, (e4 + 3u * gsize) << 2);
    }
    for (; e4 < total4; e4 += gsize) process(W4[e4], e4 << 2);

    // flush queue (loads all retired; atomics can't stall them now)
    __syncthreads();
    unsigned qn = qcount < (unsigned)QMAX ? qcount : (unsigned)QMAX;
    for (unsigned t = threadIdx.x; t < qn; t += blockDim.x) {
        unsigned wbits = qw[t], ji = qji[t];
        unsigned i = ji & 0xffffu, j = ji >> 16;
        int s = atomicAdd(&cnt[i], 1);
        if (s < CAP) { uint2 p; p.x = wbits; p.y = j;
                       epk[(size_t)i * CAP + s] = p; }
    }
}

// CSR step (chains==4 fast path): 16-lane group per (chain, column).
// Group g: i = g>>2, c = g&3 -> the 4 chains of a column share the block's
// L1 lines for epk[i*CAP..]. Edge reads are 128B-contiguous per round.
template <bool FIRST>
__global__ __launch_bounds__(256) void step_csr_kernel(
    const float* __restrict__ rv_in,    // [4, N] (unused if FIRST)
    const float* __restrict__ snaps,    // [T, N] (used if FIRST)
    float* __restrict__ rv_out,         // [4, N]
    const int* __restrict__ cnt,
    const uint2* __restrict__ epk,
    int N) {
    const int lane = threadIdx.x & 15;
    const int g    = blockIdx.x * 16 + (threadIdx.x >> 4);
    const int i    = g >> 2;            // column
    const int c    = g & 3;             // chain
    if (i >= N) return;
    const float* rv = rv_in + (size_t)c * N;
    const float* sa = snaps + (size_t)(c + 1) * N;
    const float* sb = snaps + (size_t)c * N;
    int n = cnt[i];
    if (n > CAP) n = CAP;
    float prod = 1.0f;
    for (int k = lane; k < n; k += 16) {
        uint2 p = epk[(size_t)i * CAP + k];
        float w = __uint_as_float(p.x);
        int j = (int)p.y;
        float r = FIRST ? (sa[j] - sb[j]) : rv[j];
        prod *= 1.0f - w * r;
    }
    for (int off = 8; off; off >>= 1) prod *= __shfl_xor(prod, off, 16);
    if (lane == 0) rv_out[(size_t)c * N + i] = 1.0f - prod;
}

// Generic fallback (chains != 4): 32 lanes/column, y = chain.
template <bool FIRST>
__global__ __launch_bounds__(256) void step_lp_kernel(
    const float* __restrict__ rv_in, const float* __restrict__ snaps,
    float* __restrict__ rv_out, const int* __restrict__ cnt,
    const uint2* __restrict__ epk, int N) {
    const int c    = blockIdx.y;
    const int lane = threadIdx.x & 31;
    const int i    = blockIdx.x * 8 + (threadIdx.x >> 5);
    if (i >= N) return;
    const float* rv = rv_in + (size_t)c * N;
    const float* sa = snaps + (size_t)(c + 1) * N;
    const float* sb = snaps + (size_t)c * N;
    int n = cnt[i];
    if (n > CAP) n = CAP;
    float prod = 1.0f;
    for (int k = lane; k < n; k += 32) {
        uint2 p = epk[(size_t)i * CAP + k];
        float r = FIRST ? (sa[(int)p.y] - sb[(int)p.y]) : rv[(int)p.y];
        prod *= 1.0f - __uint_as_float(p.x) * r;
    }
    for (int off = 16; off; off >>= 1) prod *= __shfl_xor(prod, off, 32);
    if (lane == 0) rv_out[(size_t)c * N + i] = 1.0f - prod;
}

extern "C" void kernel_launch(void* const* d_in, const int* in_sizes, int n_in,
                              void* d_out, int out_size, void* d_ws, size_t ws_size,
                              hipStream_t stream) {
    const float* snaps = (const float*)d_in[0];   // [T, N]
    const float* W     = (const float*)d_in[1];   // [N, N]
    // d_in[2] = time_pick (int64); step counts are static (=3)

    const int T = in_sizes[2];          // 6
    const int N = in_sizes[0] / T;      // 8192
    const int chains = T - 2;           // 4
    const int NSTEPS = 3;

    // workspace layout
    char* ws = (char*)d_ws;
    int*   cnt = (int*)ws;                                   // N ints
    size_t off = ((size_t)N * 4 + 255) & ~(size_t)255;
    float* rvA = (float*)(ws + off);                         // chains*N
    off += ((size_t)chains * N * 4 + 255) & ~(size_t)255;
    float* rvB = (float*)(ws + off);                         // chains*N
    off += ((size_t)chains * N * 4 + 255) & ~(size_t)255;
    uint2* epk = (uint2*)(ws + off);                         // N*CAP uint2 (4 MB)

    hipMemsetAsync(cnt, 0, (size_t)N * sizeof(int), stream);

    // build sparse structure: one streaming pass over W
    // (R5-proven config: 16 f4/thread -> 4096 blocks, 4-deep unroll)
    const unsigned total4 = (unsigned)((size_t)N * N / 4);
    const bool pow2 = (N & (N - 1)) == 0;
    unsigned log2N = 0;
    while ((1u << log2N) < (unsigned)N) ++log2N;
    const int bblk = 256;
    int bgrd = (int)((total4 + (unsigned)bblk * 16 - 1) / ((unsigned)bblk * 16));
    if (bgrd < 1) bgrd = 1;
    if (pow2)
        build_edges_kernel<true><<<bgrd, bblk, 0, stream>>>(
            (const floatx4*)W, total4, log2N, (unsigned)N - 1, cnt, epk, (unsigned)N);
    else
        build_edges_kernel<false><<<bgrd, bblk, 0, stream>>>(
            (const floatx4*)W, total4, log2N, (unsigned)N - 1, cnt, epk, (unsigned)N);

    float* outp = (float*)d_out;
    float* bufs[2] = {rvA, rvB};
    if (chains == 4) {
        int blocks = (N * 4 + 15) / 16;   // 16-lane group per (c,i)
        float* out0 = (NSTEPS == 1) ? outp : rvA;
        step_csr_kernel<true><<<blocks, 256, 0, stream>>>(nullptr, snaps, out0, cnt, epk, N);
        for (int s = 1; s < NSTEPS; ++s) {
            const float* in = bufs[(s - 1) & 1];
            float* out = (s == NSTEPS - 1) ? outp : bufs[s & 1];
            step_csr_kernel<false><<<blocks, 256, 0, stream>>>(in, nullptr, out, cnt, epk, N);
        }
    } else {
        dim3 sgrd((N + 7) / 8, chains);
        float* out0 = (NSTEPS == 1) ? outp : rvA;
        step_lp_kernel<true><<<sgrd, 256, 0, stream>>>(nullptr, snaps, out0, cnt, epk, N);
        for (int s = 1; s < NSTEPS; ++s) {
            const float* in = bufs[(s - 1) & 1];
            float* out = (s == NSTEPS - 1) ? outp : bufs[s & 1];
            step_lp_kernel<false><<<sgrd, 256, 0, stream>>>(in, nullptr, out, cnt, epk, N);
        }
    }
}

// Round 9
// 67.050 us; speedup vs baseline: 2.2276x; 1.0483x over previous
//
#include <hip/hip_runtime.h>
#include <hip/hip_bf16.h>

// N=8192 nodes, T=6 snapshots, chains = T-2 = 4, 3 steps per chain.
// Step: rv_new[i] = 1 - prod_j (1 - W[j][i]*rv[j]).  W ~0.2% dense.
// Pass 1 (HBM-bound): stream W once, build a CSR-style packed edge list
//   (CAP slots/col, 8B {w,j}, epk[i*CAP+k]).  Nonzeros go through a
//   per-block LDS queue so the VMEM stream stays loads-only (vmcnt is
//   issue-ordered; a global atomic mid-stream blocks later loads).
//   R9: plain grid-stride main loop (ONE sequential front per wave).
//   R5/R7/R8 data: 4-deep unroll (4 fronts) ~4.9 TB/s, 8-deep (8 fronts)
//   worse -> theory: multi-front streams hurt DRAM row locality; TLP
//   (32 waves/CU) supplies all needed MLP.
// Pass 2: 3 step dispatches; 16-lane group per (chain, column); CSR reads
//   are 128B-contiguous per round. Steps ~2us each (R8 measured-by-diff).
// Floor = reading W once: 268 MB ~= 42.6 us at 6.3 TB/s.

#define CAP  64   // slots/column; Poisson(16.4): P(>=64) ~ e^-39
#define QMAX 256  // LDS queue entries/block; lambda ~33/block at 16 f4/thread

typedef float floatx4 __attribute__((ext_vector_type(4)));

template <bool POW2>
__global__ __launch_bounds__(256, 8) void build_edges_kernel(
    const floatx4* __restrict__ W4, unsigned total4, unsigned log2N, unsigned maskN,
    int* __restrict__ cnt, uint2* __restrict__ epk, unsigned N) {
    __shared__ unsigned qcount;
    __shared__ unsigned qw[QMAX];
    __shared__ unsigned qji[QMAX];
    if (threadIdx.x == 0) qcount = 0u;
    __syncthreads();

    const unsigned gsize = gridDim.x * blockDim.x;
    unsigned e4 = blockIdx.x * blockDim.x + threadIdx.x;

    auto emit = [&](float w, unsigned j, unsigned i) {
        unsigned k = atomicAdd(&qcount, 1u);          // LDS atomic: lgkmcnt only
        if (k < QMAX) {
            qw[k]  = __float_as_uint(w);
            qji[k] = (j << 16) | i;                   // N <= 65536
        } else {                                      // ~never: direct fallback
            int s = atomicAdd(&cnt[i], 1);
            if (s < CAP) { uint2 p; p.x = __float_as_uint(w); p.y = j;
                           epk[(size_t)i * CAP + s] = p; }
        }
    };

    // single sequential front per wave; no VMEM stores/atomics in stream
    for (; e4 < total4; e4 += gsize) {
        floatx4 v = W4[e4];
        unsigned ored = __float_as_uint(v.x) | __float_as_uint(v.y) |
                        __float_as_uint(v.z) | __float_as_uint(v.w);
        if (ored == 0u) continue;                     // weights >= 0
        unsigned e = e4 << 2;
        unsigned j, i0;
        if (POW2) { j = e >> log2N; i0 = e & maskN; }
        else      { j = e / N;      i0 = e - j * N; }
#pragma unroll
        for (int t = 0; t < 4; ++t)
            if (v[t] != 0.0f) emit(v[t], j, i0 + t);
    }

    // flush queue (loads all retired; atomics can't stall them now)
    __syncthreads();
    unsigned qn = qcount < (unsigned)QMAX ? qcount : (unsigned)QMAX;
    for (unsigned t = threadIdx.x; t < qn; t += blockDim.x) {
        unsigned wbits = qw[t], ji = qji[t];
        unsigned i = ji & 0xffffu, j = ji >> 16;
        int s = atomicAdd(&cnt[i], 1);
        if (s < CAP) { uint2 p; p.x = wbits; p.y = j;
                       epk[(size_t)i * CAP + s] = p; }
    }
}

// CSR step (chains==4 fast path): 16-lane group per (chain, column).
// Group g: i = g>>2, c = g&3 -> the 4 chains of a column share the block's
// L1 lines for epk[i*CAP..]. Edge reads are 128B-contiguous per round.
template <bool FIRST>
__global__ __launch_bounds__(256) void step_csr_kernel(
    const float* __restrict__ rv_in,    // [4, N] (unused if FIRST)
    const float* __restrict__ snaps,    // [T, N] (used if FIRST)
    float* __restrict__ rv_out,         // [4, N]
    const int* __restrict__ cnt,
    const uint2* __restrict__ epk,
    int N) {
    const int lane = threadIdx.x & 15;
    const int g    = blockIdx.x * 16 + (threadIdx.x >> 4);
    const int i    = g >> 2;            // column
    const int c    = g & 3;             // chain
    if (i >= N) return;
    const float* rv = rv_in + (size_t)c * N;
    const float* sa = snaps + (size_t)(c + 1) * N;
    const float* sb = snaps + (size_t)c * N;
    int n = cnt[i];
    if (n > CAP) n = CAP;
    float prod = 1.0f;
    for (int k = lane; k < n; k += 16) {
        uint2 p = epk[(size_t)i * CAP + k];
        float w = __uint_as_float(p.x);
        int j = (int)p.y;
        float r = FIRST ? (sa[j] - sb[j]) : rv[j];
        prod *= 1.0f - w * r;
    }
    for (int off = 8; off; off >>= 1) prod *= __shfl_xor(prod, off, 16);
    if (lane == 0) rv_out[(size_t)c * N + i] = 1.0f - prod;
}

// Generic fallback (chains != 4): 32 lanes/column, y = chain.
template <bool FIRST>
__global__ __launch_bounds__(256) void step_lp_kernel(
    const float* __restrict__ rv_in, const float* __restrict__ snaps,
    float* __restrict__ rv_out, const int* __restrict__ cnt,
    const uint2* __restrict__ epk, int N) {
    const int c    = blockIdx.y;
    const int lane = threadIdx.x & 31;
    const int i    = blockIdx.x * 8 + (threadIdx.x >> 5);
    if (i >= N) return;
    const float* rv = rv_in + (size_t)c * N;
    const float* sa = snaps + (size_t)(c + 1) * N;
    const float* sb = snaps + (size_t)c * N;
    int n = cnt[i];
    if (n > CAP) n = CAP;
    float prod = 1.0f;
    for (int k = lane; k < n; k += 32) {
        uint2 p = epk[(size_t)i * CAP + k];
        float r = FIRST ? (sa[(int)p.y] - sb[(int)p.y]) : rv[(int)p.y];
        prod *= 1.0f - __uint_as_float(p.x) * r;
    }
    for (int off = 16; off; off >>= 1) prod *= __shfl_xor(prod, off, 32);
    if (lane == 0) rv_out[(size_t)c * N + i] = 1.0f - prod;
}

extern "C" void kernel_launch(void* const* d_in, const int* in_sizes, int n_in,
                              void* d_out, int out_size, void* d_ws, size_t ws_size,
                              hipStream_t stream) {
    const float* snaps = (const float*)d_in[0];   // [T, N]
    const float* W     = (const float*)d_in[1];   // [N, N]
    // d_in[2] = time_pick (int64); step counts are static (=3)

    const int T = in_sizes[2];          // 6
    const int N = in_sizes[0] / T;      // 8192
    const int chains = T - 2;           // 4
    const int NSTEPS = 3;

    // workspace layout
    char* ws = (char*)d_ws;
    int*   cnt = (int*)ws;                                   // N ints
    size_t off = ((size_t)N * 4 + 255) & ~(size_t)255;
    float* rvA = (float*)(ws + off);                         // chains*N
    off += ((size_t)chains * N * 4 + 255) & ~(size_t)255;
    float* rvB = (float*)(ws + off);                         // chains*N
    off += ((size_t)chains * N * 4 + 255) & ~(size_t)255;
    uint2* epk = (uint2*)(ws + off);                         // N*CAP uint2 (4 MB)

    hipMemsetAsync(cnt, 0, (size_t)N * sizeof(int), stream);

    // build sparse structure: one streaming pass over W
    // (grid-stride, 4096 blocks x 256 thr = 16 blocks/CU scheduled)
    const unsigned total4 = (unsigned)((size_t)N * N / 4);
    const bool pow2 = (N & (N - 1)) == 0;
    unsigned log2N = 0;
    while ((1u << log2N) < (unsigned)N) ++log2N;
    const int bblk = 256;
    int bgrd = (int)((total4 + (unsigned)bblk * 16 - 1) / ((unsigned)bblk * 16));
    if (bgrd < 1) bgrd = 1;
    if (pow2)
        build_edges_kernel<true><<<bgrd, bblk, 0, stream>>>(
            (const floatx4*)W, total4, log2N, (unsigned)N - 1, cnt, epk, (unsigned)N);
    else
        build_edges_kernel<false><<<bgrd, bblk, 0, stream>>>(
            (const floatx4*)W, total4, log2N, (unsigned)N - 1, cnt, epk, (unsigned)N);

    float* outp = (float*)d_out;
    float* bufs[2] = {rvA, rvB};
    if (chains == 4) {
        int blocks = (N * 4 + 15) / 16;   // 16-lane group per (c,i)
        float* out0 = (NSTEPS == 1) ? outp : rvA;
        step_csr_kernel<true><<<blocks, 256, 0, stream>>>(nullptr, snaps, out0, cnt, epk, N);
        for (int s = 1; s < NSTEPS; ++s) {
            const float* in = bufs[(s - 1) & 1];
            float* out = (s == NSTEPS - 1) ? outp : bufs[s & 1];
            step_csr_kernel<false><<<blocks, 256, 0, stream>>>(in, nullptr, out, cnt, epk, N);
        }
    } else {
        dim3 sgrd((N + 7) / 8, chains);
        float* out0 = (NSTEPS == 1) ? outp : rvA;
        step_lp_kernel<true><<<sgrd, 256, 0, stream>>>(nullptr, snaps, out0, cnt, epk, N);
        for (int s = 1; s < NSTEPS; ++s) {
            const float* in = bufs[(s - 1) & 1];
            float* out = (s == NSTEPS - 1) ? outp : bufs[s & 1];
            step_lp_kernel<false><<<sgrd, 256, 0, stream>>>(in, nullptr, out, cnt, epk, N);
        }
    }
}

// Round 10
// 66.964 us; speedup vs baseline: 2.2304x; 1.0013x over previous
//
#include <hip/hip_runtime.h>
#include <hip/hip_bf16.h>

// N=8192 nodes, T=6 snapshots, chains = T-2 = 4, 3 steps per chain.
// Step: rv_new[i] = 1 - prod_j (1 - W[j][i]*rv[j]).  W ~0.2% dense.
// Pass 1 (HBM-bound): stream W once, build a CSR-style packed edge list
//   (CAP slots/col, 8B {w,j}, epk[i*CAP+k]).  Nonzeros go through a
//   per-block LDS queue so the VMEM stream stays loads-only (vmcnt is
//   issue-ordered; a global atomic mid-stream blocks later loads).
//   R10: block-contiguous partitioning — each block owns one contiguous
//   64 KB chunk and advances a single sequential DRAM front (R9's
//   grid-stride still jumped 16 MB per iteration per wave; ladder:
//   4-deep unroll 70.3 -> grid-stride 67.0 -> contiguous ?).
// Pass 2: 3 step dispatches; 16-lane group per (chain, column); CSR reads
//   are 128B-contiguous per round. Steps ~2us each (R8 measured-by-diff).
// Floor = reading W once: 268 MB ~= 42.6 us at 6.3 TB/s.

#define CAP  64   // slots/column; Poisson(16.4): P(>=64) ~ e^-39
#define QMAX 256  // LDS queue entries/block; lambda ~33/block at 16 f4/thread

typedef float floatx4 __attribute__((ext_vector_type(4)));

template <bool POW2>
__global__ __launch_bounds__(256, 8) void build_edges_kernel(
    const floatx4* __restrict__ W4, unsigned total4, unsigned chunk,
    unsigned log2N, unsigned maskN,
    int* __restrict__ cnt, uint2* __restrict__ epk, unsigned N) {
    __shared__ unsigned qcount;
    __shared__ unsigned qw[QMAX];
    __shared__ unsigned qji[QMAX];
    if (threadIdx.x == 0) qcount = 0u;
    __syncthreads();

    const unsigned base = blockIdx.x * chunk;
    unsigned end = base + chunk;
    if (end > total4) end = total4;

    auto emit = [&](float w, unsigned j, unsigned i) {
        unsigned k = atomicAdd(&qcount, 1u);          // LDS atomic: lgkmcnt only
        if (k < QMAX) {
            qw[k]  = __float_as_uint(w);
            qji[k] = (j << 16) | i;                   // N <= 65536
        } else {                                      // ~never: direct fallback
            int s = atomicAdd(&cnt[i], 1);
            if (s < CAP) { uint2 p; p.x = __float_as_uint(w); p.y = j;
                           epk[(size_t)i * CAP + s] = p; }
        }
    };

    // block-contiguous sweep: 4 KB contiguous per block-iteration,
    // no VMEM stores/atomics in the load stream
    for (unsigned e4 = base + threadIdx.x; e4 < end; e4 += blockDim.x) {
        floatx4 v = W4[e4];
        unsigned ored = __float_as_uint(v.x) | __float_as_uint(v.y) |
                        __float_as_uint(v.z) | __float_as_uint(v.w);
        if (ored == 0u) continue;                     // weights >= 0
        unsigned e = e4 << 2;
        unsigned j, i0;
        if (POW2) { j = e >> log2N; i0 = e & maskN; }
        else      { j = e / N;      i0 = e - j * N; }
#pragma unroll
        for (int t = 0; t < 4; ++t)
            if (v[t] != 0.0f) emit(v[t], j, i0 + t);
    }

    // flush queue (loads all retired; atomics can't stall them now)
    __syncthreads();
    unsigned qn = qcount < (unsigned)QMAX ? qcount : (unsigned)QMAX;
    for (unsigned t = threadIdx.x; t < qn; t += blockDim.x) {
        unsigned wbits = qw[t], ji = qji[t];
        unsigned i = ji & 0xffffu, j = ji >> 16;
        int s = atomicAdd(&cnt[i], 1);
        if (s < CAP) { uint2 p; p.x = wbits; p.y = j;
                       epk[(size_t)i * CAP + s] = p; }
    }
}

// CSR step (chains==4 fast path): 16-lane group per (chain, column).
// Group g: i = g>>2, c = g&3 -> the 4 chains of a column share the block's
// L1 lines for epk[i*CAP..]. Edge reads are 128B-contiguous per round.
template <bool FIRST>
__global__ __launch_bounds__(256) void step_csr_kernel(
    const float* __restrict__ rv_in,    // [4, N] (unused if FIRST)
    const float* __restrict__ snaps,    // [T, N] (used if FIRST)
    float* __restrict__ rv_out,         // [4, N]
    const int* __restrict__ cnt,
    const uint2* __restrict__ epk,
    int N) {
    const int lane = threadIdx.x & 15;
    const int g    = blockIdx.x * 16 + (threadIdx.x >> 4);
    const int i    = g >> 2;            // column
    const int c    = g & 3;             // chain
    if (i >= N) return;
    const float* rv = rv_in + (size_t)c * N;
    const float* sa = snaps + (size_t)(c + 1) * N;
    const float* sb = snaps + (size_t)c * N;
    int n = cnt[i];
    if (n > CAP) n = CAP;
    float prod = 1.0f;
    for (int k = lane; k < n; k += 16) {
        uint2 p = epk[(size_t)i * CAP + k];
        float w = __uint_as_float(p.x);
        int j = (int)p.y;
        float r = FIRST ? (sa[j] - sb[j]) : rv[j];
        prod *= 1.0f - w * r;
    }
    for (int off = 8; off; off >>= 1) prod *= __shfl_xor(prod, off, 16);
    if (lane == 0) rv_out[(size_t)c * N + i] = 1.0f - prod;
}

// Generic fallback (chains != 4): 32 lanes/column, y = chain.
template <bool FIRST>
__global__ __launch_bounds__(256) void step_lp_kernel(
    const float* __restrict__ rv_in, const float* __restrict__ snaps,
    float* __restrict__ rv_out, const int* __restrict__ cnt,
    const uint2* __restrict__ epk, int N) {
    const int c    = blockIdx.y;
    const int lane = threadIdx.x & 31;
    const int i    = blockIdx.x * 8 + (threadIdx.x >> 5);
    if (i >= N) return;
    const float* rv = rv_in + (size_t)c * N;
    const float* sa = snaps + (size_t)(c + 1) * N;
    const float* sb = snaps + (size_t)c * N;
    int n = cnt[i];
    if (n > CAP) n = CAP;
    float prod = 1.0f;
    for (int k = lane; k < n; k += 32) {
        uint2 p = epk[(size_t)i * CAP + k];
        float r = FIRST ? (sa[(int)p.y] - sb[(int)p.y]) : rv[(int)p.y];
        prod *= 1.0f - __uint_as_float(p.x) * r;
    }
    for (int off = 16; off; off >>= 1) prod *= __shfl_xor(prod, off, 32);
    if (lane == 0) rv_out[(size_t)c * N + i] = 1.0f - prod;
}

extern "C" void kernel_launch(void* const* d_in, const int* in_sizes, int n_in,
                              void* d_out, int out_size, void* d_ws, size_t ws_size,
                              hipStream_t stream) {
    const float* snaps = (const float*)d_in[0];   // [T, N]
    const float* W     = (const float*)d_in[1];   // [N, N]
    // d_in[2] = time_pick (int64); step counts are static (=3)

    const int T = in_sizes[2];          // 6
    const int N = in_sizes[0] / T;      // 8192
    const int chains = T - 2;           // 4
    const int NSTEPS = 3;

    // workspace layout
    char* ws = (char*)d_ws;
    int*   cnt = (int*)ws;                                   // N ints
    size_t off = ((size_t)N * 4 + 255) & ~(size_t)255;
    float* rvA = (float*)(ws + off);                         // chains*N
    off += ((size_t)chains * N * 4 + 255) & ~(size_t)255;
    float* rvB = (float*)(ws + off);                         // chains*N
    off += ((size_t)chains * N * 4 + 255) & ~(size_t)255;
    uint2* epk = (uint2*)(ws + off);                         // N*CAP uint2 (4 MB)

    hipMemsetAsync(cnt, 0, (size_t)N * sizeof(int), stream);

    // build: one streaming pass over W; 4096 blocks, each owns a
    // contiguous chunk (total4/4096 = 4096 float4 = 64 KB at N=8192)
    const unsigned total4 = (unsigned)((size_t)N * N / 4);
    const bool pow2 = (N & (N - 1)) == 0;
    unsigned log2N = 0;
    while ((1u << log2N) < (unsigned)N) ++log2N;
    const int bblk = 256;
    int bgrd = 4096;
    unsigned chunk = (total4 + (unsigned)bgrd - 1) / (unsigned)bgrd;
    if (pow2)
        build_edges_kernel<true><<<bgrd, bblk, 0, stream>>>(
            (const floatx4*)W, total4, chunk, log2N, (unsigned)N - 1, cnt, epk, (unsigned)N);
    else
        build_edges_kernel<false><<<bgrd, bblk, 0, stream>>>(
            (const floatx4*)W, total4, chunk, log2N, (unsigned)N - 1, cnt, epk, (unsigned)N);

    float* outp = (float*)d_out;
    float* bufs[2] = {rvA, rvB};
    if (chains == 4) {
        int blocks = (N * 4 + 15) / 16;   // 16-lane group per (c,i)
        float* out0 = (NSTEPS == 1) ? outp : rvA;
        step_csr_kernel<true><<<blocks, 256, 0, stream>>>(nullptr, snaps, out0, cnt, epk, N);
        for (int s = 1; s < NSTEPS; ++s) {
            const float* in = bufs[(s - 1) & 1];
            float* out = (s == NSTEPS - 1) ? outp : bufs[s & 1];
            step_csr_kernel<false><<<blocks, 256, 0, stream>>>(in, nullptr, out, cnt, epk, N);
        }
    } else {
        dim3 sgrd((N + 7) / 8, chains);
        float* out0 = (NSTEPS == 1) ? outp : rvA;
        step_lp_kernel<true><<<sgrd, 256, 0, stream>>>(nullptr, snaps, out0, cnt, epk, N);
        for (int s = 1; s < NSTEPS; ++s) {
            const float* in = bufs[(s - 1) & 1];
            float* out = (s == NSTEPS - 1) ? outp : bufs[s & 1];
            step_lp_kernel<false><<<sgrd, 256, 0, stream>>>(in, nullptr, out, cnt, epk, N);
        }
    }
}